// Round 1
// 679.093 us; speedup vs baseline: 1.3777x; 1.3777x over previous
//
#include <hip/hip_runtime.h>
#include <math.h>
#include <limits.h>

#define EPSB 1e-5f
#define R2C  0.09f

// ---- workspace offsets (floats). Total ~4.44M floats = ~17.8 MB ----
#define OFF_MASKF 0          // N*16
#define OFF_KERNF 1600000    // N*16  (dead after k_prep -> merge partials live here)
#define OFF_STATS 3200000    // (unused now, kept for layout stability)
#define OFF_VT    3202048    // 128*352
#define OFF_FEATW 3247104    // 128*36
#define OFF_MZ1   3251712    // 16384*36  (dead until k_merge1 -> tower partials live here)
#define OFF_MZ2   3841536    // 16384*36
#define OFF_INT   4431360    // 256 ints (topk 128 | cand_batch 128)

// ============================ fused tower layer ===========================
// blockIdx.y = tower (0: mask, 1: kernel).
// BN stats: producer blocks write per-block partial (sum,sumsq) rows
// NON-ATOMICALLY to tp_out[(tw*gridDim.x + blk)*64 + {0..63}]; the consumer
// launch reduces gridDim.x partial rows at its head. No global atomics.
template <int COLS>
__global__ __launch_bounds__(256)
void k_tower2(const float* __restrict__ X0, const float* __restrict__ X1,
              const float* __restrict__ W0, const float* __restrict__ W1,
              const float* __restrict__ b0, const float* __restrict__ b1,
              float* __restrict__ Y0, float* __restrict__ Y1,
              const double* __restrict__ tp_in, double* __restrict__ tp_out,
              int N) {
    __shared__ float As[256 * 33];
    __shared__ float mrs[64];
    __shared__ float red[256];
    __shared__ double redd[256];
    int tid = threadIdx.x;
    int tw = blockIdx.y;
    const float* X = tw ? X1 : X0;
    const float* W = tw ? W1 : W0;
    const float* bias = tw ? b1 : b0;
    float* Y = tw ? Y1 : Y0;

    bool nrm = (tp_in != nullptr);
    if (nrm) {
        // reduce gridDim.x per-block partials (cols 0..31 = sum, 32..63 = sumsq)
        int col = tid & 63, part = tid >> 6;
        const double* src = tp_in + (size_t)tw * gridDim.x * 64;
        double acc = 0.0;
        for (int b = part; b < (int)gridDim.x; b += 4)
            acc += src[(size_t)b * 64 + col];
        redd[part * 64 + col] = acc;
        __syncthreads();
        if (tid < 32) {
            double S = redd[tid] + redd[64 + tid] + redd[128 + tid] + redd[192 + tid];
            double Q = redd[32 + tid] + redd[96 + tid] + redd[160 + tid] + redd[224 + tid];
            double m = S / (double)N;
            double v = Q / (double)N - m * m;
            mrs[tid] = (float)m; mrs[32 + tid] = (float)rsqrt(v + (double)EPSB);
        }
    }
    __syncthreads();
    int rbase = blockIdx.x * 256;
    int rmax = N - rbase; if (rmax > 256) rmax = 256;
    // ---- coalesced stage-in (+BN/ReLU) ----
    const float4* Xv = (const float4*)(X + (size_t)rbase * 32);
    for (int f = tid; f < 2048; f += 256) {
        int r = f >> 3, c0 = (f & 7) * 4;
        float4 v = make_float4(0.f, 0.f, 0.f, 0.f);
        if (r < rmax) v = Xv[f];
        float e[4] = {v.x, v.y, v.z, v.w};
        float* dst = &As[r * 33 + c0];
#pragma unroll
        for (int u = 0; u < 4; u++) {
            float t = e[u];
            if (nrm) t = fmaxf((t - mrs[c0 + u]) * mrs[32 + c0 + u], 0.f);
            dst[u] = t;
        }
    }
    __syncthreads();
    // ---- compute: one row per thread ----
    float acc[COLS];
#pragma unroll
    for (int j = 0; j < COLS; j++) acc[j] = 0.f;
    if (bias) {
#pragma unroll
        for (int j = 0; j < COLS; j++) acc[j] = bias[j];
    }
#pragma unroll 4
    for (int k = 0; k < 32; k++) {
        float a = As[tid * 33 + k];
        const float* wr = W + k * COLS;   // wave-uniform -> scalar loads
#pragma unroll
        for (int j = 0; j < COLS; j++) acc[j] = fmaf(a, wr[j], acc[j]);
    }
    // ---- BN stats: per-block partials, NO atomics ----
    if constexpr (COLS == 32) {
        if (tp_out) {
            int wv = tid >> 6;
#pragma unroll
            for (int j = 0; j < 32; j++) {
                float s = acc[j], q = acc[j] * acc[j];
#pragma unroll
                for (int off = 32; off > 0; off >>= 1) {
                    s += __shfl_down(s, off);
                    q += __shfl_down(q, off);
                }
                if ((tid & 63) == 0) { red[wv * 64 + j] = s; red[wv * 64 + 32 + j] = q; }
            }
            __syncthreads();
            if (tid < 64) {
                double s = (double)red[tid] + (double)red[64 + tid] +
                           (double)red[128 + tid] + (double)red[192 + tid];
                tp_out[((size_t)tw * gridDim.x + blockIdx.x) * 64 + tid] = s;
            }
        }
    }
    // ---- stage-out through LDS, coalesced global write ----
    __syncthreads();
#pragma unroll
    for (int j = 0; j < COLS; j++) As[tid * 33 + j] = acc[j];
    __syncthreads();
    constexpr int C4 = COLS / 4;
    for (int f = tid; f < 256 * C4; f += 256) {
        int r = f / C4, c0 = (f % C4) * 4;
        if (r < rmax) {
            const float* sp = &As[r * 33 + c0];
            float4 o = {sp[0], sp[1], sp[2], sp[3]};
            *(float4*)(Y + (size_t)(rbase + r) * COLS + c0) = o;
        }
    }
}

// ================================= NMS ====================================
#define NBINS 2048
#define NMC   1024
#define NCAP  1088
#define SLOTS 17
__global__ __launch_bounds__(1024)
void k_nms(const float* __restrict__ heat, const float* __restrict__ coords,
           const int* __restrict__ bidx, int N, int* __restrict__ topk) {
    __shared__ int   hist[NBINS];
    __shared__ float ch[NCAP], cxs[NCAP], cys[NCAP], czs[NCAP];
    __shared__ int   cid[NCAP];
    __shared__ int   sh_s, sh_e, sh_T, sh_cnt;
    __shared__ float sh_val;
    __shared__ float rv[16]; __shared__ int ri[16];
    __shared__ float fbx[32], fby[32], fbz[32];
    int b = blockIdx.x, tid = threadIdx.x;
    if (tid == 0) {
        int lo = 0, hi = N;
        while (lo < hi) { int m = (lo + hi) >> 1; if (bidx[m] < b) lo = m + 1; else hi = m; }
        sh_s = lo;
        lo = 0; hi = N;
        while (lo < hi) { int m = (lo + hi) >> 1; if (bidx[m] < b + 1) lo = m + 1; else hi = m; }
        sh_e = lo;
    }
    __syncthreads();
    int s = sh_s, e = sh_e, nb = e - s;
    if (nb <= 0) {
        if (tid < 32) topk[b * 32 + tid] = 0;
        return;
    }
    for (int i = tid; i < NBINS; i += 1024) hist[i] = 0;
    __syncthreads();
    for (int n = s + tid; n < e; n += 1024) {
        float h = heat[n];
        int bin = (int)(h * (float)NBINS);
        bin = min(max(bin, 0), NBINS - 1);
        atomicAdd(&hist[bin], 1);
    }
    __syncthreads();
    for (int off = 1; off < NBINS; off <<= 1) {
        int v[2];
#pragma unroll
        for (int u = 0; u < 2; u++) {
            int i = tid + u * 1024;
            v[u] = hist[i] + ((i + off < NBINS) ? hist[i + off] : 0);
        }
        __syncthreads();
#pragma unroll
        for (int u = 0; u < 2; u++) hist[tid + u * 1024] = v[u];
        __syncthreads();
    }
    int Meff = min(NMC, nb);
#pragma unroll
    for (int u = 0; u < 2; u++) {
        int i = tid + u * 1024;
        if (hist[i] >= Meff && (i == NBINS - 1 || hist[i + 1] < Meff)) sh_T = i;
    }
    if (tid == 0) sh_cnt = 0;
    __syncthreads();
    int T = sh_T;
    float thr = (float)T * (1.0f / (float)NBINS);
    for (int n = s + tid; n < e; n += 1024) {
        float h = heat[n];
        int bin = (int)(h * (float)NBINS);
        bin = min(max(bin, 0), NBINS - 1);
        if (bin >= T) {
            int p = atomicAdd(&sh_cnt, 1);
            if (p < NCAP) {
                ch[p] = h; cid[p] = n;
                cxs[p] = coords[(size_t)n * 3 + 0];
                cys[p] = coords[(size_t)n * 3 + 1];
                czs[p] = coords[(size_t)n * 3 + 2];
            }
        }
    }
    __syncthreads();
    int C = min(sh_cnt, NCAP);
    bool overflow = (sh_cnt > NCAP);
    if (tid < 64) {
        float hh[SLOTS], xx[SLOTS], yy[SLOTS], zz[SLOTS];
        int ii[SLOTS];
#pragma unroll
        for (int m = 0; m < SLOTS; m++) {
            int i = m * 64 + tid;
            if (i < C) { hh[m] = ch[i]; xx[m] = cxs[i]; yy[m] = cys[i]; zz[m] = czs[i]; ii[m] = cid[i]; }
            else { hh[m] = -INFINITY; xx[m] = 1e30f; yy[m] = 1e30f; zz[m] = 1e30f; ii[m] = INT_MAX; }
        }
        float last = -INFINITY;
        for (int t = 0; t < 32; t++) {
            float bv = -INFINITY, bx = 0.f, by = 0.f, bz = 0.f;
            int bo = INT_MAX;
#pragma unroll
            for (int m = 0; m < SLOTS; m++) {
                bool c = (hh[m] > bv) || (hh[m] == bv && ii[m] < bo);
                if (c) { bv = hh[m]; bo = ii[m]; bx = xx[m]; by = yy[m]; bz = zz[m]; }
            }
#pragma unroll
            for (int off = 32; off > 0; off >>= 1) {
                float ov = __shfl_down(bv, off);
                int   oo = __shfl_down(bo, off);
                float ox = __shfl_down(bx, off);
                float oy = __shfl_down(by, off);
                float oz = __shfl_down(bz, off);
                bool c = (ov > bv) || (ov == bv && oo < bo);
                if (c) { bv = ov; bo = oo; bx = ox; by = oy; bz = oz; }
            }
            bv = __shfl(bv, 0); bo = __shfl(bo, 0);
            bx = __shfl(bx, 0); by = __shfl(by, 0); bz = __shfl(bz, 0);
            if (tid == 0) topk[b * 32 + t] = bo;
            last = bv;
#pragma unroll
            for (int m = 0; m < SLOTS; m++) {
                float dx = xx[m] - bx, dy = yy[m] - by, dz = zz[m] - bz;
                if (dx * dx + dy * dy + dz * dz < R2C) hh[m] = -INFINITY;
            }
        }
        if (tid == 0) sh_val = last;
    }
    __syncthreads();
    bool sound = (!overflow) && (C > 0) && (sh_val >= thr);
    if (!sound) {
        for (int t = 0; t < 32; t++) {
            float bv = -INFINITY; int bo = INT_MAX;
            for (int n = s + tid; n < e; n += 1024) {
                float x = coords[(size_t)n * 3], y = coords[(size_t)n * 3 + 1], z = coords[(size_t)n * 3 + 2];
                bool sup = false;
                for (int u = 0; u < t; u++) {
                    float dx = x - fbx[u], dy = y - fby[u], dz = z - fbz[u];
                    if (dx * dx + dy * dy + dz * dz < R2C) { sup = true; break; }
                }
                if (!sup) {
                    float h = heat[n];
                    if (h > bv || (h == bv && n < bo)) { bv = h; bo = n; }
                }
            }
#pragma unroll
            for (int off = 32; off > 0; off >>= 1) {
                float ov = __shfl_down(bv, off); int oo = __shfl_down(bo, off);
                if (ov > bv || (ov == bv && oo < bo)) { bv = ov; bo = oo; }
            }
            if ((tid & 63) == 0) { int w = tid >> 6; rv[w] = bv; ri[w] = bo; }
            __syncthreads();
            if (tid == 0) {
                bv = rv[0]; bo = ri[0];
                for (int w = 1; w < 16; w++)
                    if (rv[w] > bv || (rv[w] == bv && ri[w] < bo)) { bv = rv[w]; bo = ri[w]; }
                if (bo == INT_MAX) bo = 0;
                topk[b * 32 + t] = bo;
                fbx[t] = coords[(size_t)bo * 3];
                fby[t] = coords[(size_t)bo * 3 + 1];
                fbz[t] = coords[(size_t)bo * 3 + 2];
            }
            __syncthreads();
        }
    }
}

// ============================ instance prep ===============================
__global__ __launch_bounds__(384)
void k_prep(const int* __restrict__ topk, const float* __restrict__ coords,
            const int* __restrict__ bidx, const float* __restrict__ maskf,
            const float* __restrict__ kernf, const float* __restrict__ Wwg,
            const float* __restrict__ bwg, float* __restrict__ Vt,
            float* __restrict__ featw, int* __restrict__ cand_batch) {
    __shared__ float ck[16], cm[16], ctr[3], wrow[337];
    int i = blockIdx.x, tid = threadIdx.x;
    int idx = topk[i];
    if (tid < 16) { ck[tid] = kernf[(size_t)idx * 16 + tid]; cm[tid] = maskf[(size_t)idx * 16 + tid]; }
    else if (tid < 19) ctr[tid - 16] = coords[(size_t)idx * 3 + (tid - 16)];
    else if (tid == 19) cand_batch[i] = bidx[idx];
    __syncthreads();
    for (int c = tid; c < 337; c += 384) {
        float acc = bwg[c];
#pragma unroll
        for (int m = 0; m < 16; m++) acc += ck[m] * Wwg[m * 337 + c];
        wrow[c] = acc;
    }
    __syncthreads();
    for (int t = tid; t < 352; t += 384) {
        float v;
        if (t < 320) {
            int k = t >> 4, j = t & 15;
            if (k < 19) v = wrow[k * 16 + j];
            else {
                v = wrow[304 + j];
#pragma unroll
                for (int p = 0; p < 3; p++) v -= ctr[p] * wrow[(16 + p) * 16 + j];
            }
        } else if (t < 336) v = wrow[320 + (t - 320)];
        else if (t == 336) v = wrow[336];
        else v = 0.f;
        Vt[(size_t)i * 352 + t] = v;
    }
    for (int t = tid; t < 36; t += 384)
        featw[i * 36 + t] = (t < 16) ? ck[t] : (t < 32) ? cm[t - 16] : (t < 35) ? ctr[t - 32] : 0.f;
}

// ============================== mask heads ================================
__global__ __launch_bounds__(256)
void k_mask(const float* __restrict__ maskf, const float* __restrict__ coords,
            const float* __restrict__ Vt, float* __restrict__ out,
            int N, int ostride) {
    int tid = threadIdx.x;
    int n = blockIdx.x * 256 + tid;
    bool valid = (n < N);
    float a[20];
    if (valid) {
        const float4* fr = (const float4*)(maskf + (size_t)n * 16);
        float4 A = fr[0], B = fr[1], C = fr[2], D = fr[3];
        a[0]=A.x; a[1]=A.y; a[2]=A.z; a[3]=A.w;
        a[4]=B.x; a[5]=B.y; a[6]=B.z; a[7]=B.w;
        a[8]=C.x; a[9]=C.y; a[10]=C.z; a[11]=C.w;
        a[12]=D.x; a[13]=D.y; a[14]=D.z; a[15]=D.w;
        a[16]=coords[(size_t)n*3]; a[17]=coords[(size_t)n*3+1]; a[18]=coords[(size_t)n*3+2];
    } else {
#pragma unroll
        for (int k = 0; k < 19; k++) a[k] = 0.f;
    }
    a[19] = 1.f;
#pragma unroll
    for (int k = 0; k < 20; k++) asm volatile("" : "+v"(a[k]));  // pin in VGPRs
    int ibase = blockIdx.y * 16;
    for (int ii = 0; ii < 16; ii++) {
        const float* __restrict__ V = Vt + (size_t)(ibase + ii) * 352;  // block-uniform -> s_load
        float h[16];
#pragma unroll
        for (int j = 0; j < 16; j++) h[j] = 0.f;
#pragma unroll
        for (int k = 0; k < 20; k++) {
            float ak = a[k];
#pragma unroll
            for (int j = 0; j < 16; j++) h[j] = fmaf(ak, V[k * 16 + j], h[j]);
        }
        float acc = V[336];
#pragma unroll
        for (int j = 0; j < 16; j++) acc = fmaf(fmaxf(h[j], 0.f), V[320 + j], acc);
        if (valid)
            out[(size_t)(ibase + ii) * ostride + n] = 1.f / (1.f + __expf(-acc));
    }
}

// ============================== merge tower ===============================
// BN stats: NO global atomics. Each block writes its partial (sum,sumsq)
// row [70 doubles] to pout[blk*70 + j]; consumer reduces 64 rows at head.
__global__ __launch_bounds__(256)
void k_merge1(const float* __restrict__ featw, const float* __restrict__ Wg,
              float* __restrict__ Z, double* __restrict__ pout) {
    __shared__ float F[128 * 36];
    __shared__ double redm[280];
    int tid = threadIdx.x;
    for (int t = tid; t < 128 * 36; t += 256) F[t] = featw[t];
    __syncthreads();
    int id = blockIdx.x * 256 + tid;
    int a = id >> 7, b = id & 127;
    float d[35];
#pragma unroll
    for (int k = 0; k < 35; k++) d[k] = fmaxf(fabsf(F[a * 36 + k] - F[b * 36 + k]), 1e-6f);
    float z[35];
#pragma unroll
    for (int j = 0; j < 35; j++) z[j] = 0.f;
    for (int k = 0; k < 35; k++) {
        float dk = d[k];
        const float* wr = Wg + k * 35;
#pragma unroll
        for (int j = 0; j < 35; j++) z[j] += dk * wr[j];
    }
    int wv = tid >> 6;
#pragma unroll
    for (int j = 0; j < 35; j++) {
        float s = z[j], q = z[j] * z[j];
#pragma unroll
        for (int off = 32; off > 0; off >>= 1) { s += __shfl_down(s, off); q += __shfl_down(q, off); }
        if ((tid & 63) == 0) { redm[wv * 70 + j] = (double)s; redm[wv * 70 + 35 + j] = (double)q; }
    }
    __syncthreads();
    if (tid < 70) {
        double t = redm[tid] + redm[70 + tid] + redm[140 + tid] + redm[210 + tid];
        pout[(size_t)blockIdx.x * 70 + tid] = t;
    }
    float* zr = Z + (size_t)id * 36;
#pragma unroll
    for (int j = 0; j < 35; j++) zr[j] = z[j];
}

__global__ __launch_bounds__(256)
void k_merge_mid(const float* __restrict__ Zin, const float* __restrict__ Wg,
                 float* __restrict__ Zout, const double* __restrict__ pin,
                 double* __restrict__ pout) {
    __shared__ float nrm[70];
    __shared__ double sred[70];
    __shared__ double redm[280];
    int tid = threadIdx.x;
    if (tid < 70) {
        double acc = 0.0;
#pragma unroll 8
        for (int b = 0; b < 64; b++) acc += pin[(size_t)b * 70 + tid];
        sred[tid] = acc;
    }
    __syncthreads();
    if (tid < 35) {
        double m = sred[tid] * (1.0 / 16384.0);
        double v = sred[35 + tid] * (1.0 / 16384.0) - m * m;
        nrm[tid] = (float)m; nrm[35 + tid] = (float)rsqrt(v + (double)EPSB);
    }
    __syncthreads();
    int id = blockIdx.x * 256 + tid;
    const float* zi = Zin + (size_t)id * 36;
    float x[35];
#pragma unroll
    for (int k = 0; k < 35; k++) x[k] = fmaxf((zi[k] - nrm[k]) * nrm[35 + k], 0.f);
    float z[35];
#pragma unroll
    for (int j = 0; j < 35; j++) z[j] = 0.f;
    for (int k = 0; k < 35; k++) {
        float dk = x[k];
        const float* wr = Wg + k * 35;
#pragma unroll
        for (int j = 0; j < 35; j++) z[j] += dk * wr[j];
    }
    int wv = tid >> 6;
#pragma unroll
    for (int j = 0; j < 35; j++) {
        float s = z[j], q = z[j] * z[j];
#pragma unroll
        for (int off = 32; off > 0; off >>= 1) { s += __shfl_down(s, off); q += __shfl_down(q, off); }
        if ((tid & 63) == 0) { redm[wv * 70 + j] = (double)s; redm[wv * 70 + 35 + j] = (double)q; }
    }
    __syncthreads();
    if (tid < 70) {
        double t = redm[tid] + redm[70 + tid] + redm[140 + tid] + redm[210 + tid];
        pout[(size_t)blockIdx.x * 70 + tid] = t;
    }
    float* zr = Zout + (size_t)id * 36;
#pragma unroll
    for (int j = 0; j < 35; j++) zr[j] = z[j];
}

__global__ __launch_bounds__(256)
void k_merge_out(const float* __restrict__ Zin, const float* __restrict__ Wout,
                 const float* __restrict__ bout, const double* __restrict__ pin,
                 const int* __restrict__ cand_batch, float* __restrict__ out,
                 int N, int ostride) {
    __shared__ float nrm[70];
    __shared__ double sred[70];
    __shared__ int cb[128];
    int tid = threadIdx.x;
    if (tid < 70) {
        double acc = 0.0;
#pragma unroll 8
        for (int b = 0; b < 64; b++) acc += pin[(size_t)b * 70 + tid];
        sred[tid] = acc;
    }
    if (tid >= 128 && tid < 256) cb[tid - 128] = cand_batch[tid - 128];
    __syncthreads();
    if (tid < 35) {
        double m = sred[tid] * (1.0 / 16384.0);
        double v = sred[35 + tid] * (1.0 / 16384.0) - m * m;
        nrm[tid] = (float)m; nrm[35 + tid] = (float)rsqrt(v + (double)EPSB);
    }
    __syncthreads();
    int id = blockIdx.x * 256 + tid;
    int a = id >> 7, b = id & 127;
    const float* zi = Zin + (size_t)id * 36;
    float s = bout[0];
    for (int k = 0; k < 35; k++)
        s += fmaxf((zi[k] - nrm[k]) * nrm[35 + k], 0.f) * Wout[k];
    float v = 1.f / (1.f + __expf(-s));
    if (cb[a] != cb[b]) v = 0.f;
    out[(size_t)a * ostride + N + b] = v;
}

// =============================== launcher =================================
extern "C" void kernel_launch(void* const* d_in, const int* in_sizes, int n_in,
                              void* d_out, int out_size, void* d_ws, size_t ws_size,
                              hipStream_t stream) {
    const float* of     = (const float*)d_in[0];
    const float* coords = (const float*)d_in[1];
    const float* heat   = (const float*)d_in[2];
    const int*   bidx   = (const int*)d_in[3];
    const float* Wm     = (const float*)d_in[4];
    const float* Wm_out = (const float*)d_in[5];
    const float* bm_out = (const float*)d_in[6];
    const float* Wk     = (const float*)d_in[7];
    const float* Wk_out = (const float*)d_in[8];
    const float* bk_out = (const float*)d_in[9];
    const float* Wg     = (const float*)d_in[10];
    const float* Wg_out = (const float*)d_in[11];
    const float* bg_out = (const float*)d_in[12];
    const float* Wwg    = (const float*)d_in[13];
    const float* bwg    = (const float*)d_in[14];
    float* out = (float*)d_out;
    float* ws  = (float*)d_ws;

    int N = in_sizes[0] / 32;          // 100000
    int ostride = N + 128;             // 100128

    float*  maskf = ws + OFF_MASKF;
    float*  kernf = ws + OFF_KERNF;
    float*  Vt    = ws + OFF_VT;
    float*  featw = ws + OFF_FEATW;
    float*  mz1   = ws + OFF_MZ1;
    float*  mz2   = ws + OFF_MZ2;
    int*    topk  = (int*)(ws + OFF_INT);
    int*    cand_batch = topk + 128;

    // tower BN partials ping-pong in mz1 region (dead until k_merge1):
    // each buffer: 2 towers * 391 blocks * 64 doubles = 50048 doubles
    double* TPA = (double*)(ws + OFF_MZ1);
    double* TPB = (double*)(ws + OFF_MZ1 + 131072);
    // merge BN partials in kernf region (dead after k_prep):
    // each: 64 blocks * 70 doubles
    double* P1 = (double*)(ws + OFF_KERNF);
    double* P2 = (double*)(ws + OFF_KERNF + 16384);
    double* P3 = (double*)(ws + OFF_KERNF + 32768);

    // tower ping-pong buffers live inside d_out (overwritten before epilogue)
    float* bufAm = out;
    float* bufBm = out + (size_t)N * 32;
    float* bufAk = out + (size_t)N * 64;
    float* bufBk = out + (size_t)N * 96;

    dim3 tg2((N + 255) / 256, 2);

    k_nms<<<4, 1024, 0, stream>>>(heat, coords, bidx, N, topk);
    // both towers per launch (blockIdx.y selects); stats partials ping-pong TPA/TPB
    k_tower2<32><<<tg2, 256, 0, stream>>>(of,    of,    Wm,        Wk,        nullptr, nullptr, bufAm, bufAk, nullptr, TPA,     N);
    k_tower2<32><<<tg2, 256, 0, stream>>>(bufAm, bufAk, Wm + 1024, Wk + 1024, nullptr, nullptr, bufBm, bufBk, TPA,     TPB,     N);
    k_tower2<32><<<tg2, 256, 0, stream>>>(bufBm, bufBk, Wm + 2048, Wk + 2048, nullptr, nullptr, bufAm, bufAk, TPB,     TPA,     N);
    k_tower2<16><<<tg2, 256, 0, stream>>>(bufAm, bufAk, Wm_out,    Wk_out,    bm_out,  bk_out,  maskf, kernf, TPA,     nullptr, N);

    k_prep<<<128, 384, 0, stream>>>(topk, coords, bidx, maskf, kernf, Wwg, bwg,
                                    Vt, featw, cand_batch);
    k_mask<<<dim3((N + 255) / 256, 8), 256, 0, stream>>>(maskf, coords, Vt, out, N, ostride);

    k_merge1<<<64, 256, 0, stream>>>(featw, Wg, mz1, P1);
    k_merge_mid<<<64, 256, 0, stream>>>(mz1, Wg + 1225, mz2, P1, P2);
    k_merge_mid<<<64, 256, 0, stream>>>(mz2, Wg + 2450, mz1, P2, P3);
    k_merge_out<<<64, 256, 0, stream>>>(mz1, Wg_out, bg_out, P3, cand_batch,
                                        out, N, ostride);
}

// Round 2
// 614.443 us; speedup vs baseline: 1.5226x; 1.1052x over previous
//
#include <hip/hip_runtime.h>
#include <math.h>
#include <limits.h>

#define EPSB 1e-5f
#define R2C  0.09f

// ---- workspace offsets (floats). Total ~4.44M floats = ~17.8 MB ----
#define OFF_MASKF 0          // N*16
#define OFF_KERNF 1600000    // N*16  (dead after k_prep -> merge partials live here)
#define OFF_STATS 3200000    // (unused now, kept for layout stability)
#define OFF_VT    3202048    // 128*352
#define OFF_FEATW 3247104    // 128*36
#define OFF_MZ1   3251712    // 16384*36  (dead until k_merge1 -> tower partials live here)
#define OFF_MZ2   3841536    // 16384*36
#define OFF_INT   4431360    // 256 ints (topk 128 | cand_batch 128)

// ============================ fused tower layer ===========================
// blockIdx.y = tower (0: mask, 1: kernel).
// BN stats: producer blocks write per-block partial (sum,sumsq) rows
// NON-ATOMICALLY to tp_out[(tw*gridDim.x + blk)*64 + {0..63}]; the consumer
// launch reduces gridDim.x partial rows at its head (4 independent fp64
// accumulators so the L2 loads pipeline instead of serializing on the chain).
template <int COLS>
__global__ __launch_bounds__(256)
void k_tower2(const float* __restrict__ X0, const float* __restrict__ X1,
              const float* __restrict__ W0, const float* __restrict__ W1,
              const float* __restrict__ b0, const float* __restrict__ b1,
              float* __restrict__ Y0, float* __restrict__ Y1,
              const double* __restrict__ tp_in, double* __restrict__ tp_out,
              int N) {
    __shared__ float As[256 * 33];
    __shared__ float mrs[64];
    __shared__ float red[256];
    __shared__ double redd[256];
    int tid = threadIdx.x;
    int tw = blockIdx.y;
    const float* X = tw ? X1 : X0;
    const float* W = tw ? W1 : W0;
    const float* bias = tw ? b1 : b0;
    float* Y = tw ? Y1 : Y0;

    bool nrm = (tp_in != nullptr);
    if (nrm) {
        // reduce gridDim.x per-block partials (cols 0..31 = sum, 32..63 = sumsq)
        int col = tid & 63, part = tid >> 6;
        const double* src = tp_in + (size_t)tw * gridDim.x * 64 + col;
        int nb = (int)gridDim.x;
        double a0 = 0.0, a1 = 0.0, a2 = 0.0, a3 = 0.0;
        int b = part;
        for (; b + 12 < nb; b += 16) {
            a0 += src[(size_t)b * 64];
            a1 += src[(size_t)(b + 4) * 64];
            a2 += src[(size_t)(b + 8) * 64];
            a3 += src[(size_t)(b + 12) * 64];
        }
        for (; b < nb; b += 4) a0 += src[(size_t)b * 64];
        redd[part * 64 + col] = (a0 + a1) + (a2 + a3);
        __syncthreads();
        if (tid < 32) {
            double S = redd[tid] + redd[64 + tid] + redd[128 + tid] + redd[192 + tid];
            double Q = redd[32 + tid] + redd[96 + tid] + redd[160 + tid] + redd[224 + tid];
            double m = S / (double)N;
            double v = Q / (double)N - m * m;
            mrs[tid] = (float)m; mrs[32 + tid] = (float)rsqrt(v + (double)EPSB);
        }
    }
    __syncthreads();
    int rbase = blockIdx.x * 256;
    int rmax = N - rbase; if (rmax > 256) rmax = 256;
    // ---- coalesced stage-in (+BN/ReLU) ----
    const float4* Xv = (const float4*)(X + (size_t)rbase * 32);
    for (int f = tid; f < 2048; f += 256) {
        int r = f >> 3, c0 = (f & 7) * 4;
        float4 v = make_float4(0.f, 0.f, 0.f, 0.f);
        if (r < rmax) v = Xv[f];
        float e[4] = {v.x, v.y, v.z, v.w};
        float* dst = &As[r * 33 + c0];
#pragma unroll
        for (int u = 0; u < 4; u++) {
            float t = e[u];
            if (nrm) t = fmaxf((t - mrs[c0 + u]) * mrs[32 + c0 + u], 0.f);
            dst[u] = t;
        }
    }
    __syncthreads();
    // ---- compute: one row per thread ----
    float acc[COLS];
#pragma unroll
    for (int j = 0; j < COLS; j++) acc[j] = 0.f;
    if (bias) {
#pragma unroll
        for (int j = 0; j < COLS; j++) acc[j] = bias[j];
    }
#pragma unroll 4
    for (int k = 0; k < 32; k++) {
        float a = As[tid * 33 + k];
        const float* wr = W + k * COLS;   // wave-uniform -> scalar loads
#pragma unroll
        for (int j = 0; j < COLS; j++) acc[j] = fmaf(a, wr[j], acc[j]);
    }
    // ---- BN stats: per-block partials, NO atomics ----
    if constexpr (COLS == 32) {
        if (tp_out) {
            int wv = tid >> 6;
#pragma unroll
            for (int j = 0; j < 32; j++) {
                float s = acc[j], q = acc[j] * acc[j];
#pragma unroll
                for (int off = 32; off > 0; off >>= 1) {
                    s += __shfl_down(s, off);
                    q += __shfl_down(q, off);
                }
                if ((tid & 63) == 0) { red[wv * 64 + j] = s; red[wv * 64 + 32 + j] = q; }
            }
            __syncthreads();
            if (tid < 64) {
                double s = (double)red[tid] + (double)red[64 + tid] +
                           (double)red[128 + tid] + (double)red[192 + tid];
                tp_out[((size_t)tw * gridDim.x + blockIdx.x) * 64 + tid] = s;
            }
        }
    }
    // ---- stage-out through LDS, coalesced global write ----
    __syncthreads();
#pragma unroll
    for (int j = 0; j < COLS; j++) As[tid * 33 + j] = acc[j];
    __syncthreads();
    constexpr int C4 = COLS / 4;
    for (int f = tid; f < 256 * C4; f += 256) {
        int r = f / C4, c0 = (f % C4) * 4;
        if (r < rmax) {
            const float* sp = &As[r * 33 + c0];
            float4 o = {sp[0], sp[1], sp[2], sp[3]};
            *(float4*)(Y + (size_t)(rbase + r) * COLS + c0) = o;
        }
    }
}

// ================================= NMS ====================================
#define NBINS 2048
#define NMC   1024
#define NCAP  1088
#define SLOTS 17
__global__ __launch_bounds__(1024)
void k_nms(const float* __restrict__ heat, const float* __restrict__ coords,
           const int* __restrict__ bidx, int N, int* __restrict__ topk) {
    __shared__ int   hist[NBINS];
    __shared__ float ch[NCAP], cxs[NCAP], cys[NCAP], czs[NCAP];
    __shared__ int   cid[NCAP];
    __shared__ int   sh_s, sh_e, sh_T, sh_cnt;
    __shared__ float sh_val;
    __shared__ float rv[16]; __shared__ int ri[16];
    __shared__ float fbx[32], fby[32], fbz[32];
    int b = blockIdx.x, tid = threadIdx.x;
    if (tid == 0) {
        int lo = 0, hi = N;
        while (lo < hi) { int m = (lo + hi) >> 1; if (bidx[m] < b) lo = m + 1; else hi = m; }
        sh_s = lo;
        lo = 0; hi = N;
        while (lo < hi) { int m = (lo + hi) >> 1; if (bidx[m] < b + 1) lo = m + 1; else hi = m; }
        sh_e = lo;
    }
    __syncthreads();
    int s = sh_s, e = sh_e, nb = e - s;
    if (nb <= 0) {
        if (tid < 32) topk[b * 32 + tid] = 0;
        return;
    }
    for (int i = tid; i < NBINS; i += 1024) hist[i] = 0;
    __syncthreads();
    for (int n = s + tid; n < e; n += 1024) {
        float h = heat[n];
        int bin = (int)(h * (float)NBINS);
        bin = min(max(bin, 0), NBINS - 1);
        atomicAdd(&hist[bin], 1);
    }
    __syncthreads();
    for (int off = 1; off < NBINS; off <<= 1) {
        int v[2];
#pragma unroll
        for (int u = 0; u < 2; u++) {
            int i = tid + u * 1024;
            v[u] = hist[i] + ((i + off < NBINS) ? hist[i + off] : 0);
        }
        __syncthreads();
#pragma unroll
        for (int u = 0; u < 2; u++) hist[tid + u * 1024] = v[u];
        __syncthreads();
    }
    int Meff = min(NMC, nb);
#pragma unroll
    for (int u = 0; u < 2; u++) {
        int i = tid + u * 1024;
        if (hist[i] >= Meff && (i == NBINS - 1 || hist[i + 1] < Meff)) sh_T = i;
    }
    if (tid == 0) sh_cnt = 0;
    __syncthreads();
    int T = sh_T;
    float thr = (float)T * (1.0f / (float)NBINS);
    for (int n = s + tid; n < e; n += 1024) {
        float h = heat[n];
        int bin = (int)(h * (float)NBINS);
        bin = min(max(bin, 0), NBINS - 1);
        if (bin >= T) {
            int p = atomicAdd(&sh_cnt, 1);
            if (p < NCAP) {
                ch[p] = h; cid[p] = n;
                cxs[p] = coords[(size_t)n * 3 + 0];
                cys[p] = coords[(size_t)n * 3 + 1];
                czs[p] = coords[(size_t)n * 3 + 2];
            }
        }
    }
    __syncthreads();
    int C = min(sh_cnt, NCAP);
    bool overflow = (sh_cnt > NCAP);
    if (tid < 64) {
        float hh[SLOTS], xx[SLOTS], yy[SLOTS], zz[SLOTS];
        int ii[SLOTS];
#pragma unroll
        for (int m = 0; m < SLOTS; m++) {
            int i = m * 64 + tid;
            if (i < C) { hh[m] = ch[i]; xx[m] = cxs[i]; yy[m] = cys[i]; zz[m] = czs[i]; ii[m] = cid[i]; }
            else { hh[m] = -INFINITY; xx[m] = 1e30f; yy[m] = 1e30f; zz[m] = 1e30f; ii[m] = INT_MAX; }
        }
        float last = -INFINITY;
        for (int t = 0; t < 32; t++) {
            float bv = -INFINITY, bx = 0.f, by = 0.f, bz = 0.f;
            int bo = INT_MAX;
#pragma unroll
            for (int m = 0; m < SLOTS; m++) {
                bool c = (hh[m] > bv) || (hh[m] == bv && ii[m] < bo);
                if (c) { bv = hh[m]; bo = ii[m]; bx = xx[m]; by = yy[m]; bz = zz[m]; }
            }
#pragma unroll
            for (int off = 32; off > 0; off >>= 1) {
                float ov = __shfl_down(bv, off);
                int   oo = __shfl_down(bo, off);
                float ox = __shfl_down(bx, off);
                float oy = __shfl_down(by, off);
                float oz = __shfl_down(bz, off);
                bool c = (ov > bv) || (ov == bv && oo < bo);
                if (c) { bv = ov; bo = oo; bx = ox; by = oy; bz = oz; }
            }
            bv = __shfl(bv, 0); bo = __shfl(bo, 0);
            bx = __shfl(bx, 0); by = __shfl(by, 0); bz = __shfl(bz, 0);
            if (tid == 0) topk[b * 32 + t] = bo;
            last = bv;
#pragma unroll
            for (int m = 0; m < SLOTS; m++) {
                float dx = xx[m] - bx, dy = yy[m] - by, dz = zz[m] - bz;
                if (dx * dx + dy * dy + dz * dz < R2C) hh[m] = -INFINITY;
            }
        }
        if (tid == 0) sh_val = last;
    }
    __syncthreads();
    bool sound = (!overflow) && (C > 0) && (sh_val >= thr);
    if (!sound) {
        for (int t = 0; t < 32; t++) {
            float bv = -INFINITY; int bo = INT_MAX;
            for (int n = s + tid; n < e; n += 1024) {
                float x = coords[(size_t)n * 3], y = coords[(size_t)n * 3 + 1], z = coords[(size_t)n * 3 + 2];
                bool sup = false;
                for (int u = 0; u < t; u++) {
                    float dx = x - fbx[u], dy = y - fby[u], dz = z - fbz[u];
                    if (dx * dx + dy * dy + dz * dz < R2C) { sup = true; break; }
                }
                if (!sup) {
                    float h = heat[n];
                    if (h > bv || (h == bv && n < bo)) { bv = h; bo = n; }
                }
            }
#pragma unroll
            for (int off = 32; off > 0; off >>= 1) {
                float ov = __shfl_down(bv, off); int oo = __shfl_down(bo, off);
                if (ov > bv || (ov == bv && oo < bo)) { bv = ov; bo = oo; }
            }
            if ((tid & 63) == 0) { int w = tid >> 6; rv[w] = bv; ri[w] = bo; }
            __syncthreads();
            if (tid == 0) {
                bv = rv[0]; bo = ri[0];
                for (int w = 1; w < 16; w++)
                    if (rv[w] > bv || (rv[w] == bv && ri[w] < bo)) { bv = rv[w]; bo = ri[w]; }
                if (bo == INT_MAX) bo = 0;
                topk[b * 32 + t] = bo;
                fbx[t] = coords[(size_t)bo * 3];
                fby[t] = coords[(size_t)bo * 3 + 1];
                fbz[t] = coords[(size_t)bo * 3 + 2];
            }
            __syncthreads();
        }
    }
}

// ============================ instance prep ===============================
__global__ __launch_bounds__(384)
void k_prep(const int* __restrict__ topk, const float* __restrict__ coords,
            const int* __restrict__ bidx, const float* __restrict__ maskf,
            const float* __restrict__ kernf, const float* __restrict__ Wwg,
            const float* __restrict__ bwg, float* __restrict__ Vt,
            float* __restrict__ featw, int* __restrict__ cand_batch) {
    __shared__ float ck[16], cm[16], ctr[3], wrow[337];
    int i = blockIdx.x, tid = threadIdx.x;
    int idx = topk[i];
    if (tid < 16) { ck[tid] = kernf[(size_t)idx * 16 + tid]; cm[tid] = maskf[(size_t)idx * 16 + tid]; }
    else if (tid < 19) ctr[tid - 16] = coords[(size_t)idx * 3 + (tid - 16)];
    else if (tid == 19) cand_batch[i] = bidx[idx];
    __syncthreads();
    for (int c = tid; c < 337; c += 384) {
        float acc = bwg[c];
#pragma unroll
        for (int m = 0; m < 16; m++) acc += ck[m] * Wwg[m * 337 + c];
        wrow[c] = acc;
    }
    __syncthreads();
    for (int t = tid; t < 352; t += 384) {
        float v;
        if (t < 320) {
            int k = t >> 4, j = t & 15;
            if (k < 19) v = wrow[k * 16 + j];
            else {
                v = wrow[304 + j];
#pragma unroll
                for (int p = 0; p < 3; p++) v -= ctr[p] * wrow[(16 + p) * 16 + j];
            }
        } else if (t < 336) v = wrow[320 + (t - 320)];
        else if (t == 336) v = wrow[336];
        else v = 0.f;
        Vt[(size_t)i * 352 + t] = v;
    }
    for (int t = tid; t < 36; t += 384)
        featw[i * 36 + t] = (t < 16) ? ck[t] : (t < 32) ? cm[t - 16] : (t < 35) ? ctr[t - 32] : 0.f;
}

// ============================== mask heads ================================
// One point per thread; 8 instances per blockIdx.y slice. a[20] is re-pinned
// in VGPRs at the TOP OF EVERY ii ITERATION (the old one-shot pin let the
// allocator shrink to 20 VGPRs and reload maskf/coords per use -> FETCH 31MB,
// 2x VALU overhead). V accessed via block-uniform pointer -> s_load.
#define MASK_PER 8
__global__ __launch_bounds__(256)
void k_mask(const float* __restrict__ maskf, const float* __restrict__ coords,
            const float* __restrict__ Vt, float* __restrict__ out,
            int N, int ostride) {
    int tid = threadIdx.x;
    int n = blockIdx.x * 256 + tid;
    bool valid = (n < N);
    int nc = valid ? n : (N - 1);
    float a[20];
    {
        const float4* fr = (const float4*)(maskf + (size_t)nc * 16);
        float4 A = fr[0], B = fr[1], C = fr[2], D = fr[3];
        a[0]=A.x; a[1]=A.y; a[2]=A.z; a[3]=A.w;
        a[4]=B.x; a[5]=B.y; a[6]=B.z; a[7]=B.w;
        a[8]=C.x; a[9]=C.y; a[10]=C.z; a[11]=C.w;
        a[12]=D.x; a[13]=D.y; a[14]=D.z; a[15]=D.w;
        a[16]=coords[(size_t)nc*3]; a[17]=coords[(size_t)nc*3+1]; a[18]=coords[(size_t)nc*3+2];
    }
    a[19] = 1.f;
    int ibase = blockIdx.y * MASK_PER;
    const float* __restrict__ V = Vt + (size_t)ibase * 352;   // block-uniform
    float* op = out + (size_t)ibase * ostride + n;
    for (int ii = 0; ii < MASK_PER; ii++) {
#pragma unroll
        for (int k = 0; k < 20; k++) asm volatile("" : "+v"(a[k]));  // keep resident
        float h[16];
#pragma unroll
        for (int j = 0; j < 16; j++) h[j] = 0.f;
#pragma unroll
        for (int k = 0; k < 20; k++) {
            float ak = a[k];
#pragma unroll
            for (int j = 0; j < 16; j++) h[j] = fmaf(ak, V[k * 16 + j], h[j]);
        }
        float acc = V[336];
#pragma unroll
        for (int j = 0; j < 16; j++) acc = fmaf(fmaxf(h[j], 0.f), V[320 + j], acc);
        if (valid) *op = 1.f / (1.f + __expf(-acc));
        V += 352; op += ostride;
    }
}

// ============================== merge tower ===============================
// BN stats: NO global atomics. Each block writes its partial (sum,sumsq)
// row [70 doubles] to pout[blk*70 + j]; consumer reduces 64 rows at head
// with 4 independent accumulators (fully unrolled -> loads pipeline).
__global__ __launch_bounds__(256)
void k_merge1(const float* __restrict__ featw, const float* __restrict__ Wg,
              float* __restrict__ Z, double* __restrict__ pout) {
    __shared__ float F[128 * 36];
    __shared__ double redm[280];
    int tid = threadIdx.x;
    for (int t = tid; t < 128 * 36; t += 256) F[t] = featw[t];
    __syncthreads();
    int id = blockIdx.x * 256 + tid;
    int a = id >> 7, b = id & 127;
    float d[35];
#pragma unroll
    for (int k = 0; k < 35; k++) d[k] = fmaxf(fabsf(F[a * 36 + k] - F[b * 36 + k]), 1e-6f);
    float z[35];
#pragma unroll
    for (int j = 0; j < 35; j++) z[j] = 0.f;
    for (int k = 0; k < 35; k++) {
        float dk = d[k];
        const float* wr = Wg + k * 35;
#pragma unroll
        for (int j = 0; j < 35; j++) z[j] += dk * wr[j];
    }
    int wv = tid >> 6;
#pragma unroll
    for (int j = 0; j < 35; j++) {
        float s = z[j], q = z[j] * z[j];
#pragma unroll
        for (int off = 32; off > 0; off >>= 1) { s += __shfl_down(s, off); q += __shfl_down(q, off); }
        if ((tid & 63) == 0) { redm[wv * 70 + j] = (double)s; redm[wv * 70 + 35 + j] = (double)q; }
    }
    __syncthreads();
    if (tid < 70) {
        double t = redm[tid] + redm[70 + tid] + redm[140 + tid] + redm[210 + tid];
        pout[(size_t)blockIdx.x * 70 + tid] = t;
    }
    float* zr = Z + (size_t)id * 36;
#pragma unroll
    for (int j = 0; j < 35; j++) zr[j] = z[j];
}

__global__ __launch_bounds__(256)
void k_merge_mid(const float* __restrict__ Zin, const float* __restrict__ Wg,
                 float* __restrict__ Zout, const double* __restrict__ pin,
                 double* __restrict__ pout) {
    __shared__ float nrm[70];
    __shared__ double sred[70];
    __shared__ double redm[280];
    int tid = threadIdx.x;
    if (tid < 70) {
        double a0 = 0.0, a1 = 0.0, a2 = 0.0, a3 = 0.0;
#pragma unroll
        for (int b = 0; b < 64; b += 4) {
            a0 += pin[(size_t)b * 70 + tid];
            a1 += pin[(size_t)(b + 1) * 70 + tid];
            a2 += pin[(size_t)(b + 2) * 70 + tid];
            a3 += pin[(size_t)(b + 3) * 70 + tid];
        }
        sred[tid] = (a0 + a1) + (a2 + a3);
    }
    __syncthreads();
    if (tid < 35) {
        double m = sred[tid] * (1.0 / 16384.0);
        double v = sred[35 + tid] * (1.0 / 16384.0) - m * m;
        nrm[tid] = (float)m; nrm[35 + tid] = (float)rsqrt(v + (double)EPSB);
    }
    __syncthreads();
    int id = blockIdx.x * 256 + tid;
    const float* zi = Zin + (size_t)id * 36;
    float x[35];
#pragma unroll
    for (int k = 0; k < 35; k++) x[k] = fmaxf((zi[k] - nrm[k]) * nrm[35 + k], 0.f);
    float z[35];
#pragma unroll
    for (int j = 0; j < 35; j++) z[j] = 0.f;
    for (int k = 0; k < 35; k++) {
        float dk = x[k];
        const float* wr = Wg + k * 35;
#pragma unroll
        for (int j = 0; j < 35; j++) z[j] += dk * wr[j];
    }
    int wv = tid >> 6;
#pragma unroll
    for (int j = 0; j < 35; j++) {
        float s = z[j], q = z[j] * z[j];
#pragma unroll
        for (int off = 32; off > 0; off >>= 1) { s += __shfl_down(s, off); q += __shfl_down(q, off); }
        if ((tid & 63) == 0) { redm[wv * 70 + j] = (double)s; redm[wv * 70 + 35 + j] = (double)q; }
    }
    __syncthreads();
    if (tid < 70) {
        double t = redm[tid] + redm[70 + tid] + redm[140 + tid] + redm[210 + tid];
        pout[(size_t)blockIdx.x * 70 + tid] = t;
    }
    float* zr = Zout + (size_t)id * 36;
#pragma unroll
    for (int j = 0; j < 35; j++) zr[j] = z[j];
}

__global__ __launch_bounds__(256)
void k_merge_out(const float* __restrict__ Zin, const float* __restrict__ Wout,
                 const float* __restrict__ bout, const double* __restrict__ pin,
                 const int* __restrict__ cand_batch, float* __restrict__ out,
                 int N, int ostride) {
    __shared__ float nrm[70];
    __shared__ double sred[70];
    __shared__ int cb[128];
    int tid = threadIdx.x;
    if (tid < 70) {
        double a0 = 0.0, a1 = 0.0, a2 = 0.0, a3 = 0.0;
#pragma unroll
        for (int b = 0; b < 64; b += 4) {
            a0 += pin[(size_t)b * 70 + tid];
            a1 += pin[(size_t)(b + 1) * 70 + tid];
            a2 += pin[(size_t)(b + 2) * 70 + tid];
            a3 += pin[(size_t)(b + 3) * 70 + tid];
        }
        sred[tid] = (a0 + a1) + (a2 + a3);
    }
    if (tid >= 128 && tid < 256) cb[tid - 128] = cand_batch[tid - 128];
    __syncthreads();
    if (tid < 35) {
        double m = sred[tid] * (1.0 / 16384.0);
        double v = sred[35 + tid] * (1.0 / 16384.0) - m * m;
        nrm[tid] = (float)m; nrm[35 + tid] = (float)rsqrt(v + (double)EPSB);
    }
    __syncthreads();
    int id = blockIdx.x * 256 + tid;
    int a = id >> 7, b = id & 127;
    const float* zi = Zin + (size_t)id * 36;
    float s = bout[0];
    for (int k = 0; k < 35; k++)
        s += fmaxf((zi[k] - nrm[k]) * nrm[35 + k], 0.f) * Wout[k];
    float v = 1.f / (1.f + __expf(-s));
    if (cb[a] != cb[b]) v = 0.f;
    out[(size_t)a * ostride + N + b] = v;
}

// =============================== launcher =================================
extern "C" void kernel_launch(void* const* d_in, const int* in_sizes, int n_in,
                              void* d_out, int out_size, void* d_ws, size_t ws_size,
                              hipStream_t stream) {
    const float* of     = (const float*)d_in[0];
    const float* coords = (const float*)d_in[1];
    const float* heat   = (const float*)d_in[2];
    const int*   bidx   = (const int*)d_in[3];
    const float* Wm     = (const float*)d_in[4];
    const float* Wm_out = (const float*)d_in[5];
    const float* bm_out = (const float*)d_in[6];
    const float* Wk     = (const float*)d_in[7];
    const float* Wk_out = (const float*)d_in[8];
    const float* bk_out = (const float*)d_in[9];
    const float* Wg     = (const float*)d_in[10];
    const float* Wg_out = (const float*)d_in[11];
    const float* bg_out = (const float*)d_in[12];
    const float* Wwg    = (const float*)d_in[13];
    const float* bwg    = (const float*)d_in[14];
    float* out = (float*)d_out;
    float* ws  = (float*)d_ws;

    int N = in_sizes[0] / 32;          // 100000
    int ostride = N + 128;             // 100128

    float*  maskf = ws + OFF_MASKF;
    float*  kernf = ws + OFF_KERNF;
    float*  Vt    = ws + OFF_VT;
    float*  featw = ws + OFF_FEATW;
    float*  mz1   = ws + OFF_MZ1;
    float*  mz2   = ws + OFF_MZ2;
    int*    topk  = (int*)(ws + OFF_INT);
    int*    cand_batch = topk + 128;

    // tower BN partials ping-pong in mz1 region (dead until k_merge1):
    double* TPA = (double*)(ws + OFF_MZ1);
    double* TPB = (double*)(ws + OFF_MZ1 + 131072);
    // merge BN partials in kernf region (dead after k_prep):
    double* P1 = (double*)(ws + OFF_KERNF);
    double* P2 = (double*)(ws + OFF_KERNF + 16384);
    double* P3 = (double*)(ws + OFF_KERNF + 32768);

    // tower ping-pong buffers live inside d_out (overwritten before epilogue)
    float* bufAm = out;
    float* bufBm = out + (size_t)N * 32;
    float* bufAk = out + (size_t)N * 64;
    float* bufBk = out + (size_t)N * 96;

    dim3 tg2((N + 255) / 256, 2);

    k_nms<<<4, 1024, 0, stream>>>(heat, coords, bidx, N, topk);
    // both towers per launch (blockIdx.y selects); stats partials ping-pong TPA/TPB
    k_tower2<32><<<tg2, 256, 0, stream>>>(of,    of,    Wm,        Wk,        nullptr, nullptr, bufAm, bufAk, nullptr, TPA,     N);
    k_tower2<32><<<tg2, 256, 0, stream>>>(bufAm, bufAk, Wm + 1024, Wk + 1024, nullptr, nullptr, bufBm, bufBk, TPA,     TPB,     N);
    k_tower2<32><<<tg2, 256, 0, stream>>>(bufBm, bufBk, Wm + 2048, Wk + 2048, nullptr, nullptr, bufAm, bufAk, TPB,     TPA,     N);
    k_tower2<16><<<tg2, 256, 0, stream>>>(bufAm, bufAk, Wm_out,    Wk_out,    bm_out,  bk_out,  maskf, kernf, TPA,     nullptr, N);

    k_prep<<<128, 384, 0, stream>>>(topk, coords, bidx, maskf, kernf, Wwg, bwg,
                                    Vt, featw, cand_batch);
    k_mask<<<dim3((N + 255) / 256, 16), 256, 0, stream>>>(maskf, coords, Vt, out, N, ostride);

    k_merge1<<<64, 256, 0, stream>>>(featw, Wg, mz1, P1);
    k_merge_mid<<<64, 256, 0, stream>>>(mz1, Wg + 1225, mz2, P1, P2);
    k_merge_mid<<<64, 256, 0, stream>>>(mz2, Wg + 2450, mz1, P2, P3);
    k_merge_out<<<64, 256, 0, stream>>>(mz1, Wg_out, bg_out, P3, cand_batch,
                                        out, N, ostride);
}